// Round 10
// baseline (743.873 us; speedup 1.0000x reference)
//
#include <hip/hip_runtime.h>

typedef float f32x4  __attribute__((ext_vector_type(4)));
typedef float f32x16 __attribute__((ext_vector_type(16)));
typedef int   i32x4  __attribute__((ext_vector_type(4)));
typedef int   i32x8  __attribute__((ext_vector_type(8)));

#define T_DIM 8192
#define H_DIM 4096
#define SC1 0x7f7f7f7f   // e8m0 scale = 127 -> 2^0 = 1.0 in all 4 bytes

__device__ __forceinline__ unsigned int pack_fp8x4(float a, float b, float c, float d) {
    int v = __builtin_amdgcn_cvt_pk_fp8_f32(a, b, 0, false);
    v = __builtin_amdgcn_cvt_pk_fp8_f32(c, d, v, true);
    return (unsigned int)v;
}

// ---------------------------------------------------------------------------
// BOTH GEMM operands are frag-major so the K-loop needs NO LDS and NO barriers:
// qx (A):  addr = ((r>>5)*64 + kt)*2048 + lane*32 + byte,
//          lane = ((k>>5)&1)*32 + (r&31), byte = k&31.
// wqT (B): addr = ((((l*16+bn)*64+kt)*4+wc)*2+n2)*2048 + lane*32 + byte,
//          lane = ((k>>5)&1)*32 + (n&31).
// A wave's frag load = ONE coalesced 2KB read (base + lane*32).
// ---------------------------------------------------------------------------

// w[l][k][n] f32  ->  wqT[l] frag-major fp8(e4m3)
__global__ __launch_bounds__(256) void wquant_kernel(
    const float* __restrict__ w, unsigned char* __restrict__ wqT)
{
    const int l  = blockIdx.z;
    const int n0 = blockIdx.x * 64;
    const int k0 = blockIdx.y * 64;
    const int tid = threadIdx.x;
    __shared__ unsigned char tile[64][68];   // [k][n]
    const float* wl = w + (size_t)l * H_DIM * H_DIM;
#pragma unroll
    for (int p = 0; p < 4; ++p) {
        int r = p * 16 + (tid >> 4);         // k within tile
        int c = (tid & 15) * 4;              // n within tile
        f32x4 v = *(const f32x4*)(wl + (size_t)(k0 + r) * H_DIM + n0 + c);
        *(unsigned int*)&tile[r][c] = pack_fp8x4(v[0], v[1], v[2], v[3]);
    }
    __syncthreads();
    const int nl = tid >> 2;                 // n within tile
    const int g  = tid & 3;                  // 16B k-chunk within 64
    unsigned int words[4];
#pragma unroll
    for (int wi = 0; wi < 4; ++wi) {
        unsigned int a = 0;
#pragma unroll
        for (int b = 0; b < 4; ++b)
            a |= (unsigned int)tile[g * 16 + wi * 4 + b][nl] << (8 * b);
        words[wi] = a;
    }
    const int bn = n0 >> 8, wc = (n0 >> 6) & 3, kt = k0 >> 6;
    const int n2 = nl >> 5;
    const int lane = (g >> 1) * 32 + (nl & 31);
    const int byte0 = (g & 1) * 16;
    const size_t off = ((((size_t)l * 16 + bn) * 64 + kt) * 4 + wc) * 2 + n2;
    unsigned char* op = wqT + off * 2048 + lane * 32 + byte0;
    uint4 ov; ov.x = words[0]; ov.y = words[1]; ov.z = words[2]; ov.w = words[3];
    *(uint4*)op = ov;
}

// ---------------- row-wise RMSNorm (+relu) (+quant) ----------------
// MODE 0: x = relu(in); resid_out = x; qx = fp8 (FRAG-MAJOR)
// MODE 1: x = in;                      qx = fp8 (FRAG-MAJOR)
// MODE 2: x = in;                      out = f32 rms(x)*g (plain)
template <int MODE>
__global__ __launch_bounds__(256) void row_kernel(
    const float* __restrict__ in,
    float* __restrict__ resid_out,
    void* __restrict__ out,
    const float* __restrict__ g,
    const float* __restrict__ scale_p)
{
    const int row = blockIdx.x;
    const int tid = threadIdx.x;
    const float* rin = in + (size_t)row * H_DIM;
    float x[16];
    float ss = 0.0f;
#pragma unroll
    for (int j = 0; j < 4; ++j) {
        const int base = (j * 256 + tid) * 4;
        f32x4 v = *(const f32x4*)(rin + base);
        f32x4 rv;
#pragma unroll
        for (int i = 0; i < 4; ++i) {
            float t = v[i];
            if (MODE == 0) t = fmaxf(t, 0.0f);
            x[j * 4 + i] = t;
            rv[i] = t;
            ss += t * t;
        }
        if (MODE == 0)
            *(f32x4*)(resid_out + (size_t)row * H_DIM + base) = rv;
    }
#pragma unroll
    for (int off = 32; off > 0; off >>= 1)
        ss += __shfl_down(ss, off, 64);
    __shared__ float red[4];
    if ((tid & 63) == 0) red[tid >> 6] = ss;
    __syncthreads();
    const float var  = (red[0] + red[1] + red[2] + red[3]) * (1.0f / (float)H_DIM);
    const float rinv = 1.0f / sqrtf(var + 1e-6f);

    if (MODE == 2) {
        float* ro = (float*)out + (size_t)row * H_DIM;
#pragma unroll
        for (int j = 0; j < 4; ++j) {
            const int base = (j * 256 + tid) * 4;
            f32x4 gv = *(const f32x4*)(g + base);
            f32x4 ov;
#pragma unroll
            for (int i = 0; i < 4; ++i) ov[i] = (x[j * 4 + i] * rinv) * gv[i];
            *(f32x4*)(ro + base) = ov;
        }
    } else {
        const float s = scale_p[0];
        unsigned int* qo = (unsigned int*)out;
        const int mrow = row >> 5, rl = row & 31;
#pragma unroll
        for (int j = 0; j < 4; ++j) {
            const int base = (j * 256 + tid) * 4;
            f32x4 gv = *(const f32x4*)(g + base);
            float q[4];
#pragma unroll
            for (int i = 0; i < 4; ++i) {
                float y = (x[j * 4 + i] * rinv) * gv[i];
                y = y / s;
                q[i] = fminf(fmaxf(y, -448.0f), 448.0f);
            }
            // frag-major word index: W=j*256+tid covers k=4W..4W+3
            const int W  = j * 256 + tid;
            const int kt = W >> 4, kh = (W >> 3) & 1, wb = W & 7;
            const size_t widx =
                (((size_t)mrow * 64 + kt) * 64 + (kh * 32 + rl)) * 8 + wb;
            qo[widx] = pack_fp8x4(q[0], q[1], q[2], q[3]);
        }
    }
}

// ---- MX-fp8 GEMM, 256x256 tile, BK=64: NO LDS, NO barriers, all-direct ----
#define MM2(m, P) do {                                                          \
    acc[m][0] = __builtin_amdgcn_mfma_scale_f32_32x32x64_f8f6f4(                \
        fa[m], b##P##0, acc[m][0], 0, 0, 0, SC1, 0, SC1);                       \
    acc[m][1] = __builtin_amdgcn_mfma_scale_f32_32x32x64_f8f6f4(                \
        fa[m], b##P##1, acc[m][1], 0, 0, 0, SC1, 0, SC1);                       \
} while (0)

// tile t (parity P): MFMA pairs; after fa[m]'s last use, reload it for t+1;
// then prefetch B(t+2) into this parity's regs. Compiler counts vmcnt.
#define TILE(P) do {                                                            \
    MM2(0, P); fa[0] = *(const i32x8*)(gAm0 + ka);                              \
    MM2(1, P); fa[1] = *(const i32x8*)(gAm1 + ka);                              \
    MM2(2, P); fa[2] = *(const i32x8*)(gAm2 + ka);                              \
    MM2(3, P); fa[3] = *(const i32x8*)(gAm3 + ka);                              \
    ka += 2048;                                                                 \
    b##P##0 = *(const i32x8*)(gB0 + kb);                                        \
    b##P##1 = *(const i32x8*)(gB0 + kb + 2048);                                 \
    kb += 16384;                                                                \
} while (0)

__global__ __launch_bounds__(512, 2) void gemm_fp8_kernel(
    const unsigned char* __restrict__ A,   // qx, frag-major
    const unsigned char* __restrict__ B,   // wqT layer, frag-major
    float* __restrict__ C,
    const float* __restrict__ s_in,
    const float* __restrict__ s_w)
{
    const float alpha = s_in[0] * s_w[0];

    // XCD-bijective swizzle (512 blocks = 64/XCD) + 8x8 supertile per XCD
    const int b = blockIdx.x;
    const int local = b >> 3, chunk = b & 7;         // chunk = XCD id
    const int bm = (chunk & 3) * 8 + (local & 7);    // M/256 = 32
    const int bn = (chunk >> 2) * 8 + (local >> 3);  // N/256 = 16

    const int tid  = threadIdx.x;
    const int wave = tid >> 6;
    const int lane = tid & 63;
    const int wr   = wave >> 2;   // 2 M-waves
    const int wc   = wave & 3;    // 4 N-waves

    // A frag bases: mrow = bm*8 + wr*4 + m; stride per m = 64*2048 = 131072
    const unsigned char* gAm0 =
        A + ((size_t)(bm * 8 + wr * 4) * 64) * 2048 + lane * 32;
    const unsigned char* gAm1 = gAm0 + 131072;
    const unsigned char* gAm2 = gAm0 + 2 * 131072;
    const unsigned char* gAm3 = gAm0 + 3 * 131072;
    // B frag base: (bn, kt=0, wc, n2=0); per-tile stride 16384, n2 stride 2048
    const unsigned char* gB0 =
        B + (((size_t)bn * 256 + wc) * 2) * 2048 + lane * 32;

    f32x16 acc[4][2];
#pragma unroll
    for (int m = 0; m < 4; ++m)
#pragma unroll
        for (int n = 0; n < 2; ++n)
#pragma unroll
            for (int e = 0; e < 16; ++e) acc[m][n][e] = 0.0f;

    i32x8 fa[4], bX0, bX1, bY0, bY1;

    // prologue: A(0), B(0)->X, B(1)->Y
    fa[0] = *(const i32x8*)(gAm0);
    fa[1] = *(const i32x8*)(gAm1);
    fa[2] = *(const i32x8*)(gAm2);
    fa[3] = *(const i32x8*)(gAm3);
    bX0 = *(const i32x8*)(gB0);
    bX1 = *(const i32x8*)(gB0 + 2048);
    bY0 = *(const i32x8*)(gB0 + 16384);
    bY1 = *(const i32x8*)(gB0 + 16384 + 2048);
    int ka = 2048;        // A prefetch -> tile 1
    int kb = 2 * 16384;   // B prefetch -> tile 2

    // tiles 0..61 (even=X, odd=Y); prefetch stays in-bounds (max tile 63)
#pragma unroll 1
    for (int it = 0; it < 31; ++it) {
        TILE(X);
        TILE(Y);
    }
    // t = 62: compute with X; load A(63); no B prefetch
    MM2(0, X); fa[0] = *(const i32x8*)(gAm0 + ka);
    MM2(1, X); fa[1] = *(const i32x8*)(gAm1 + ka);
    MM2(2, X); fa[2] = *(const i32x8*)(gAm2 + ka);
    MM2(3, X); fa[3] = *(const i32x8*)(gAm3 + ka);
    // t = 63
    MM2(0, Y); MM2(1, Y); MM2(2, Y); MM2(3, Y);

    // epilogue: C += acc*alpha
    // (32x32 C/D: col = lane&31, row = (e&3) + 8*(e>>2) + 4*(lane>>5))
    const int lrow0 = bm * 256 + wr * 128 + 4 * (lane >> 5);
    const int lcol0 = bn * 256 + wc * 64 + (lane & 31);
#pragma unroll
    for (int m = 0; m < 4; ++m) {
#pragma unroll
        for (int n = 0; n < 2; ++n) {
#pragma unroll
            for (int e = 0; e < 16; ++e) {
                const int row = lrow0 + m * 32 + (e & 3) + 8 * (e >> 2);
                float* cp = C + (size_t)row * H_DIM + lcol0 + n * 32;
                *cp = acc[m][n][e] * alpha + *cp;
            }
        }
    }
}

extern "C" void kernel_launch(void* const* d_in, const int* in_sizes, int n_in,
                              void* d_out, int out_size, void* d_ws, size_t ws_size,
                              hipStream_t stream) {
    const float* h   = (const float*)d_in[0];   // [8192,4096]
    const float* nw  = (const float*)d_in[1];   // [4,4096]
    const float* w   = (const float*)d_in[2];   // [3,4096,4096]
    const float* wsc = (const float*)d_in[3];   // [3]
    const float* sc  = (const float*)d_in[4];   // [3]
    float* out = (float*)d_out;

    unsigned char* wqT = (unsigned char*)d_ws;                       // 3*16M fp8
    unsigned char* qx  = wqT + (size_t)3 * H_DIM * H_DIM;            // 33.5M fp8
    float* resid = (float*)(qx + (size_t)T_DIM * H_DIM);             // 134M f32

    const size_t WSTRIDE = (size_t)H_DIM * H_DIM;

    wquant_kernel<<<dim3(64, 64, 3), 256, 0, stream>>>(w, wqT);

    row_kernel<0><<<T_DIM, 256, 0, stream>>>(h, resid, qx, nw + 0 * H_DIM, sc + 0);
    gemm_fp8_kernel<<<512, 512, 0, stream>>>(qx, wqT + 0 * WSTRIDE, resid, sc + 0, wsc + 0);

    row_kernel<1><<<T_DIM, 256, 0, stream>>>(resid, nullptr, qx, nw + 1 * H_DIM, sc + 1);
    gemm_fp8_kernel<<<512, 512, 0, stream>>>(qx, wqT + 1 * WSTRIDE, resid, sc + 1, wsc + 1);

    row_kernel<1><<<T_DIM, 256, 0, stream>>>(resid, nullptr, qx, nw + 2 * H_DIM, sc + 2);
    gemm_fp8_kernel<<<512, 512, 0, stream>>>(qx, wqT + 2 * WSTRIDE, resid, sc + 2, wsc + 2);

    row_kernel<2><<<T_DIM, 256, 0, stream>>>(resid, nullptr, out, nw + 3 * H_DIM, nullptr);
}